// Round 2
// baseline (593.512 us; speedup 1.0000x reference)
//
#include <hip/hip_runtime.h>
#include <hip/hip_bf16.h>

typedef __bf16 bf16_t;
typedef __bf16 bf16x8 __attribute__((ext_vector_type(8)));
typedef __bf16 bf16x4 __attribute__((ext_vector_type(4)));
typedef float  f32x4  __attribute__((ext_vector_type(4)));

constexpr int K_IC = 4096;   // inner dim
constexpr int N_OC = 4096;   // output channels
constexpr int GROUPS = 32;   // quant groups (group size 128)

// ---------------------------------------------------------------------------
// Fused prep: blocks [0, M) do token quant; blocks [M, M+N_OC) do W dequant.
// ---------------------------------------------------------------------------
__global__ __launch_bounds__(256) void prep_kernel(const float* __restrict__ x,
                                                   const int* __restrict__ qweight,
                                                   const int* __restrict__ zeros,
                                                   const int* __restrict__ qstep,
                                                   const float* __restrict__ base_scales,
                                                   const float* __restrict__ step_scales,
                                                   bf16_t* __restrict__ qx,
                                                   bf16_t* __restrict__ w,
                                                   float* __restrict__ x_scales,
                                                   int M) {
    const int tid = threadIdx.x;
    if ((int)blockIdx.x < M) {
        // ---- token-wise int8 quant (qx stored as bf16; |q|<=127 exact) ----
        const int m = blockIdx.x;
        const float4* xr = (const float4*)(x + (size_t)m * K_IC);
        float4 v[4];
        float amax = 0.f;
#pragma unroll
        for (int i = 0; i < 4; ++i) {
            v[i] = xr[i * 256 + tid];
            amax = fmaxf(amax, fmaxf(fmaxf(fabsf(v[i].x), fabsf(v[i].y)),
                                     fmaxf(fabsf(v[i].z), fabsf(v[i].w))));
        }
#pragma unroll
        for (int off = 32; off > 0; off >>= 1)
            amax = fmaxf(amax, __shfl_xor(amax, off, 64));
        __shared__ float wmax[4];
        if ((tid & 63) == 0) wmax[tid >> 6] = amax;
        __syncthreads();
        amax = fmaxf(fmaxf(wmax[0], wmax[1]), fmaxf(wmax[2], wmax[3]));

        const float scale = amax / 127.0f;       // reference x_scales (un-clamped)
        if (tid == 0) x_scales[m] = scale;
        const float inv = 1.0f / fmaxf(scale, 1e-8f);

        bf16x4* qr = (bf16x4*)(qx + (size_t)m * K_IC);
#pragma unroll
        for (int i = 0; i < 4; ++i) {
            float e0 = fminf(fmaxf(rintf(v[i].x * inv), -127.f), 127.f);
            float e1 = fminf(fmaxf(rintf(v[i].y * inv), -127.f), 127.f);
            float e2 = fminf(fmaxf(rintf(v[i].z * inv), -127.f), 127.f);
            float e3 = fminf(fmaxf(rintf(v[i].w * inv), -127.f), 127.f);
            bf16x4 o;
            o[0] = (bf16_t)e0; o[1] = (bf16_t)e1; o[2] = (bf16_t)e2; o[3] = (bf16_t)e3;
            qr[i * 256 + tid] = o;
        }
    } else {
        // ---- grouped-int4 dequant: W = (qw - zero) * (base + step*qstep) ----
        const int oc = blockIdx.x - M;
        const float base = base_scales[oc];
        const float step = step_scales[oc];
        const int4* qwr = (const int4*)(qweight + (size_t)oc * K_IC);
        bf16x4* wr = (bf16x4*)(w + (size_t)oc * K_IC);
#pragma unroll
        for (int i = 0; i < 4; ++i) {
            const int idx = i * 256 + tid;          // int4 index within the row
            const int g = idx >> 5;                 // 32 int4 per group of 128
            const float zp = (float)zeros[oc * GROUPS + g];
            const float sc = base + step * (float)qstep[oc * GROUPS + g];
            int4 a = qwr[idx];
            bf16x4 o;
            o[0] = (bf16_t)(((float)a.x - zp) * sc);
            o[1] = (bf16_t)(((float)a.y - zp) * sc);
            o[2] = (bf16_t)(((float)a.z - zp) * sc);
            o[3] = (bf16_t)(((float)a.w - zp) * sc);
            wr[idx] = o;
        }
    }
}

// ---------------------------------------------------------------------------
// bf16 GEMM, m97 structure + XOR LDS swizzle to kill the 16-way bank conflict.
// LDS physical chunk p (16B) at (row, p) holds logical chunk c = p ^ (row&7).
// Row stride is 128 B == 32 banks, so without the swizzle 16 fragment rows
// alias to one 4-bank group (measured: 1.0e8 SQ_LDS_BANK_CONFLICT, R1).
// ---------------------------------------------------------------------------
#define BM 128
#define BN 128
#define BK 64

__device__ inline void async16(const bf16_t* g, bf16_t* l) {
    __builtin_amdgcn_global_load_lds(
        (const __attribute__((address_space(1))) void*)g,
        (__attribute__((address_space(3))) void*)l,
        16, 0, 0);
}

__global__ __launch_bounds__(256) void gemm_kernel(const bf16_t* __restrict__ A,
                                                   const bf16_t* __restrict__ B,
                                                   const float* __restrict__ x_scales,
                                                   float* __restrict__ out) {
    __shared__ __attribute__((aligned(16))) bf16_t As[BM][BK];
    __shared__ __attribute__((aligned(16))) bf16_t Bs[BN][BK];

    const int tid = threadIdx.x;
    const int lane = tid & 63;
    const int wave = tid >> 6;
    const int waveM = wave >> 1;
    const int waveN = wave & 1;
    const int bn = blockIdx.x;
    const int bm = blockIdx.y;

    f32x4 acc[4][4] = {};

    // staging: LDS dest = wave-uniform base + lane*16 (required by global_load_lds)
    // physical chunk p = tid&7 at row = tid>>3; global source chunk = p ^ (row&7)
    const int rowOff = tid >> 3;                              // 0..31, +32 per it
    const int srcCol = (((tid & 7) ^ ((tid >> 3) & 7))) * 8;  // swizzled source col
    const int dstCol = (tid & 7) * 8;                         // physical LDS col
    const bf16_t* Aptr = A + (size_t)(bm * BM + rowOff) * K_IC + srcCol;
    const bf16_t* Bptr = B + (size_t)(bn * BN + rowOff) * K_IC + srcCol;

    const int mrow = waveM * 64 + (lane & 15);
    const int nrow = waveN * 64 + (lane & 15);
    const int cq = lane >> 4;        // logical chunk quarter (0..3)
    const int sw = lane & 7;         // row&7 of every fragment row this lane reads

    for (int kt = 0; kt < K_IC / BK; ++kt) {
        const int k0 = kt * BK;
#pragma unroll
        for (int it = 0; it < 4; ++it) {
            async16(Aptr + (size_t)(it * 32) * K_IC + k0, &As[rowOff + it * 32][dstCol]);
            async16(Bptr + (size_t)(it * 32) * K_IC + k0, &Bs[rowOff + it * 32][dstCol]);
        }
        __syncthreads();

#pragma unroll
        for (int kk = 0; kk < 2; ++kk) {
            const int colA = ((kk * 4 + cq) ^ sw) * 8;   // swizzled physical column
            bf16x8 af[4], bfr[4];
#pragma unroll
            for (int i = 0; i < 4; ++i) {
                af[i]  = *(const bf16x8*)&As[mrow + i * 16][colA];
                bfr[i] = *(const bf16x8*)&Bs[nrow + i * 16][colA];
            }
#pragma unroll
            for (int i = 0; i < 4; ++i)
#pragma unroll
                for (int j = 0; j < 4; ++j)
                    acc[i][j] = __builtin_amdgcn_mfma_f32_16x16x32_bf16(af[i], bfr[j], acc[i][j], 0, 0, 0);
        }
        __syncthreads();
    }

    // epilogue: C/D layout col=lane&15, row=(lane>>4)*4+reg (m89/m91 verified)
    const int colT = lane & 15;
    const int rgrp = lane >> 4;
#pragma unroll
    for (int i = 0; i < 4; ++i) {
#pragma unroll
        for (int r = 0; r < 4; ++r) {
            const int gr = bm * BM + waveM * 64 + i * 16 + rgrp * 4 + r;
            const float sc = x_scales[gr];
#pragma unroll
            for (int j = 0; j < 4; ++j) {
                const int gc = bn * BN + waveN * 64 + j * 16 + colT;
                out[(size_t)gr * N_OC + gc] = acc[i][j][r] * sc;
            }
        }
    }
}

// ---------------------------------------------------------------------------
extern "C" void kernel_launch(void* const* d_in, const int* in_sizes, int n_in,
                              void* d_out, int out_size, void* d_ws, size_t ws_size,
                              hipStream_t stream) {
    const float* x          = (const float*)d_in[0];
    const int*   qweight    = (const int*)d_in[1];
    const int*   zeros      = (const int*)d_in[2];
    const int*   qstep      = (const int*)d_in[3];
    const float* base_scale = (const float*)d_in[4];
    const float* step_scale = (const float*)d_in[5];
    float* out = (float*)d_out;

    const int M = in_sizes[0] / K_IC;   // 8192 tokens

    char* ws = (char*)d_ws;
    bf16_t* qx = (bf16_t*)ws;                                   // M*K*2   = 64 MiB
    bf16_t* W  = (bf16_t*)(ws + (size_t)M * K_IC * 2);          // N*K*2   = 32 MiB
    float*  xs = (float*)(ws + (size_t)M * K_IC * 2 + (size_t)N_OC * K_IC * 2); // M*4

    prep_kernel<<<M + N_OC, 256, 0, stream>>>(x, qweight, zeros, qstep,
                                              base_scale, step_scale, qx, W, xs, M);

    dim3 grid(N_OC / BN, M / BM);
    gemm_kernel<<<grid, 256, 0, stream>>>(qx, W, xs, out);
}

// Round 3
// 459.716 us; speedup vs baseline: 1.2910x; 1.2910x over previous
//
#include <hip/hip_runtime.h>
#include <hip/hip_bf16.h>

typedef int   i32x4 __attribute__((ext_vector_type(4)));
typedef float f32x4 __attribute__((ext_vector_type(4)));

constexpr int K_IC = 4096;   // inner dim
constexpr int N_OC = 4096;   // output channels
constexpr int GROUPS = 32;   // quant groups (group size 128)

// ---------------------------------------------------------------------------
// Fused prep: blocks [0, M) token quant -> int8; blocks [M, M+N_OC) weight
// prep -> w8 = qw - zero (int8, fits: range [-15,15]) + sT[g][oc] scales.
// ---------------------------------------------------------------------------
__global__ __launch_bounds__(256) void prep_kernel(const float* __restrict__ x,
                                                   const int* __restrict__ qweight,
                                                   const int* __restrict__ zeros,
                                                   const int* __restrict__ qstep,
                                                   const float* __restrict__ base_scales,
                                                   const float* __restrict__ step_scales,
                                                   char* __restrict__ qx8,
                                                   char* __restrict__ w8,
                                                   float* __restrict__ sT,
                                                   float* __restrict__ x_scales,
                                                   int M) {
    const int tid = threadIdx.x;
    if ((int)blockIdx.x < M) {
        // ---- token-wise int8 quant ----
        const int m = blockIdx.x;
        const float4* xr = (const float4*)(x + (size_t)m * K_IC);
        float4 v[4];
        float amax = 0.f;
#pragma unroll
        for (int i = 0; i < 4; ++i) {
            v[i] = xr[i * 256 + tid];
            amax = fmaxf(amax, fmaxf(fmaxf(fabsf(v[i].x), fabsf(v[i].y)),
                                     fmaxf(fabsf(v[i].z), fabsf(v[i].w))));
        }
#pragma unroll
        for (int off = 32; off > 0; off >>= 1)
            amax = fmaxf(amax, __shfl_xor(amax, off, 64));
        __shared__ float wmax[4];
        if ((tid & 63) == 0) wmax[tid >> 6] = amax;
        __syncthreads();
        amax = fmaxf(fmaxf(wmax[0], wmax[1]), fmaxf(wmax[2], wmax[3]));

        const float scale = amax / 127.0f;       // reference x_scales (un-clamped)
        if (tid == 0) x_scales[m] = scale;
        const float inv = 1.0f / fmaxf(scale, 1e-8f);

        char4* qr = (char4*)(qx8 + (size_t)m * K_IC);
#pragma unroll
        for (int i = 0; i < 4; ++i) {
            char4 o;
            o.x = (char)(int)fminf(fmaxf(rintf(v[i].x * inv), -127.f), 127.f);
            o.y = (char)(int)fminf(fmaxf(rintf(v[i].y * inv), -127.f), 127.f);
            o.z = (char)(int)fminf(fmaxf(rintf(v[i].z * inv), -127.f), 127.f);
            o.w = (char)(int)fminf(fmaxf(rintf(v[i].w * inv), -127.f), 127.f);
            qr[i * 256 + tid] = o;
        }
    } else {
        // ---- weight prep: w8 = qw - zero;  sT[g][oc] = base + step*qstep ----
        const int oc = blockIdx.x - M;
        const int4* qwr = (const int4*)(qweight + (size_t)oc * K_IC);
        char4* wr = (char4*)(w8 + (size_t)oc * K_IC);
#pragma unroll
        for (int i = 0; i < 4; ++i) {
            const int idx = i * 256 + tid;          // int4 index within the row
            const int g = idx >> 5;                 // 32 int4 per group of 128
            const int zp = zeros[oc * GROUPS + g];
            int4 a = qwr[idx];
            char4 o;
            o.x = (char)(a.x - zp); o.y = (char)(a.y - zp);
            o.z = (char)(a.z - zp); o.w = (char)(a.w - zp);
            wr[idx] = o;
        }
        if (tid < GROUPS) {
            sT[(size_t)tid * N_OC + oc] =
                base_scales[oc] + step_scales[oc] * (float)qstep[oc * GROUPS + tid];
        }
    }
}

// ---------------------------------------------------------------------------
// int8 MFMA GEMM with per-group (BK=128 = group size) fp32 rescale.
// A8=[M][K] qx8, B8=[N][K] w8 (both K-major). 128x128 tile, 4 waves (2x2),
// wave does 64x64 via 4x4 tiles of mfma_i32_16x16x64_i8 (2 ksteps/group).
// XOR swizzle on 16B chunks kills the row-stride-128B bank conflict (R1/R2).
// Per group: accF[i][j] += sT[g][col_j] * (float)P[i][j]; P exact (<2^18).
// ---------------------------------------------------------------------------
#define BM 128
#define BN 128
#define BK 128

__device__ inline void async16(const char* g, char* l) {
    __builtin_amdgcn_global_load_lds(
        (const __attribute__((address_space(1))) void*)g,
        (__attribute__((address_space(3))) void*)l,
        16, 0, 0);
}

__global__ __launch_bounds__(256) void gemm_kernel(const char* __restrict__ A8,
                                                   const char* __restrict__ B8,
                                                   const float* __restrict__ sT,
                                                   const float* __restrict__ x_scales,
                                                   float* __restrict__ out) {
    __shared__ __attribute__((aligned(16))) char As[BM][BK];
    __shared__ __attribute__((aligned(16))) char Bs[BN][BK];

    const int tid = threadIdx.x;
    const int lane = tid & 63;
    const int wave = tid >> 6;
    const int waveM = wave >> 1;
    const int waveN = wave & 1;
    const int bn = blockIdx.x;
    const int bm = blockIdx.y;

    f32x4 accF[4][4] = {};
    const i32x4 zeroq = {0, 0, 0, 0};   // persistent MFMA C-init (D != C)

    // staging: LDS dest = wave-uniform base + lane*16 (global_load_lds rule)
    // physical 16B chunk p = tid&7 at row tid>>3; global source chunk p^(row&7)
    const int rowOff = tid >> 3;                                   // 0..31, +32/it
    const int srcCol = (((tid & 7) ^ ((tid >> 3) & 7))) * 16;      // bytes
    const int dstCol = (tid & 7) * 16;                             // bytes
    const char* Aptr = A8 + (size_t)(bm * BM + rowOff) * K_IC + srcCol;
    const char* Bptr = B8 + (size_t)(bn * BN + rowOff) * K_IC + srcCol;

    const int mrow = waveM * 64 + (lane & 15);
    const int nrow = waveN * 64 + (lane & 15);
    const int q = lane >> 4;         // K-quad (16 bytes each)
    const int sw = lane & 7;         // row&7 of every fragment row this lane reads

    const int colBase = bn * BN + waveN * 64 + (lane & 15);  // col for j=0

    for (int g = 0; g < GROUPS; ++g) {         // one group == one K-tile (128)
        const int k0 = g * BK;
#pragma unroll
        for (int it = 0; it < 4; ++it) {
            async16(Aptr + (size_t)(it * 32) * K_IC + k0, &As[rowOff + it * 32][dstCol]);
            async16(Bptr + (size_t)(it * 32) * K_IC + k0, &Bs[rowOff + it * 32][dstCol]);
        }
        // per-column group scales for this g (L2-hot, covered by MFMA latency)
        float scol[4];
        const float* sg = sT + (size_t)g * N_OC + colBase;
#pragma unroll
        for (int j = 0; j < 4; ++j) scol[j] = sg[j * 16];

        __syncthreads();

        i32x4 af[2][4], bfr[2][4];
#pragma unroll
        for (int kk = 0; kk < 2; ++kk) {
            const int colA = ((kk * 4 + q) ^ sw) * 16;   // swizzled physical bytes
#pragma unroll
            for (int i = 0; i < 4; ++i) {
                af[kk][i]  = *(const i32x4*)&As[mrow + i * 16][colA];
                bfr[kk][i] = *(const i32x4*)&Bs[nrow + i * 16][colA];
            }
        }
#pragma unroll
        for (int i = 0; i < 4; ++i)
#pragma unroll
            for (int j = 0; j < 4; ++j) {
                i32x4 p = __builtin_amdgcn_mfma_i32_16x16x64_i8(af[0][i], bfr[0][j], zeroq, 0, 0, 0);
                p = __builtin_amdgcn_mfma_i32_16x16x64_i8(af[1][i], bfr[1][j], p, 0, 0, 0);
#pragma unroll
                for (int r = 0; r < 4; ++r)
                    accF[i][j][r] += scol[j] * (float)p[r];
            }
        __syncthreads();
    }

    // epilogue: C/D layout col=lane&15, row=(lane>>4)*4+reg (dtype-independent)
    const int colT = lane & 15;
    const int rgrp = lane >> 4;
#pragma unroll
    for (int i = 0; i < 4; ++i) {
#pragma unroll
        for (int r = 0; r < 4; ++r) {
            const int gr = bm * BM + waveM * 64 + i * 16 + rgrp * 4 + r;
            const float sc = x_scales[gr];
#pragma unroll
            for (int j = 0; j < 4; ++j) {
                const int gc = bn * BN + waveN * 64 + j * 16 + colT;
                out[(size_t)gr * N_OC + gc] = accF[i][j][r] * sc;
            }
        }
    }
}

// ---------------------------------------------------------------------------
extern "C" void kernel_launch(void* const* d_in, const int* in_sizes, int n_in,
                              void* d_out, int out_size, void* d_ws, size_t ws_size,
                              hipStream_t stream) {
    const float* x          = (const float*)d_in[0];
    const int*   qweight    = (const int*)d_in[1];
    const int*   zeros      = (const int*)d_in[2];
    const int*   qstep      = (const int*)d_in[3];
    const float* base_scale = (const float*)d_in[4];
    const float* step_scale = (const float*)d_in[5];
    float* out = (float*)d_out;

    const int M = in_sizes[0] / K_IC;   // 8192 tokens

    char* ws = (char*)d_ws;
    char*  qx8 = ws;                                         // M*K    = 32 MiB
    char*  w8  = ws + (size_t)M * K_IC;                      // N*K    = 16 MiB
    float* sT  = (float*)(w8 + (size_t)N_OC * K_IC);         // G*N*4  = 512 KiB
    float* xs  = sT + (size_t)GROUPS * N_OC;                 // M*4    = 32 KiB

    prep_kernel<<<M + N_OC, 256, 0, stream>>>(x, qweight, zeros, qstep,
                                              base_scale, step_scale,
                                              qx8, w8, sT, xs, M);

    dim3 grid(N_OC / BN, M / BM);
    gemm_kernel<<<grid, 256, 0, stream>>>(qx8, w8, sT, xs, out);
}